// Round 4
// baseline (237.901 us; speedup 1.0000x reference)
//
#include <hip/hip_runtime.h>
#include <hip/hip_bf16.h>
#include <cstddef>
#include <cstdint>

// Problem dims
constexpr int Nn = 4096;
constexpr int Ss = 128;
constexpr int Ff = 128;
constexpr int Dd = 256;
constexpr float EPSV = 1e-8f;

// d_out layout (floats): h_o [N*D], C_new [N*S*F], k [N*F], r [N*F]
constexpr size_t HO_OFF = 0;
constexpr size_t C_OFF  = (size_t)Nn * Dd;
constexpr size_t K_OFF  = C_OFF + (size_t)Nn * Ss * Ff;
constexpr size_t R_OFF  = K_OFF + (size_t)Nn * Ff;

typedef __attribute__((ext_vector_type(4))) float f4v;   // MFMA C/D frag / NT access
typedef __attribute__((ext_vector_type(8))) short bh8;   // MFMA A/B frag (8 bf16)
typedef __attribute__((ext_vector_type(4))) short bh4;   // 4 bf16 (8 B)

__device__ __forceinline__ float sigmf(float x) { return 1.0f / (1.0f + __expf(-x)); }

__device__ __forceinline__ short f2bf(float x) {
    __hip_bfloat16 h = __float2bfloat16(x);   // RNE
    return *reinterpret_cast<short*>(&h);
}
__device__ __forceinline__ float bf2f(short s) {
    return __uint_as_float(((unsigned int)(unsigned short)s) << 16);
}

// ---------------------------------------------------------------------------
// MFMA core pieces (64x64 tile, BK=32, 4 waves 2x2, 16x16x32 bf16 frags).
// LDS 16B k-slot XOR-swizzled by (row&3): max 4-way conflict on ds_read_b128.
// ---------------------------------------------------------------------------

// ---------------------------------------------------------------------------
// Dual GEMM (blockIdx.z selects config):  out[n,j] = A[n,:K] . W[j,:K] + b[j]
// z=0: gh = h_prev @ Whh.T  (K=256)   z=1: gi = r @ Wih.T  (K=128). J=768.
// Software prefetch of next K-chunk during MFMA.
// ---------------------------------------------------------------------------
__global__ __launch_bounds__(256) void gemm_dual(
    const float* __restrict__ A0, int K0, const float* __restrict__ W0,
    const float* __restrict__ bias0, float* __restrict__ out0,
    const float* __restrict__ A1, int K1, const float* __restrict__ W1,
    const float* __restrict__ bias1, float* __restrict__ out1, int J)
{
    __shared__ __align__(16) short sA[64 * 32];
    __shared__ __align__(16) short sW[64 * 32];

    const float* A;  const float* W;  const float* bias;  float* out;  int K;
    if (blockIdx.z == 0) { A = A0; W = W0; bias = bias0; out = out0; K = K0; }
    else                 { A = A1; W = W1; bias = bias1; out = out1; K = K1; }

    const int t  = threadIdx.x;
    const int bm = blockIdx.x * 64;
    const int bj = blockIdx.y * 64;

    const int r  = t >> 2;
    const int kg = t & 3;
    const float* aRow = A + (size_t)(bm + r) * K;
    const float* wRow = W + (size_t)(bj + r) * K;
    const int swzSt = r * 32 + ((kg ^ (r & 3)) << 3);

    const int l   = t & 63;
    const int wv  = t >> 6;
    const int wr  = wv >> 1;
    const int wc  = wv & 1;
    const int kgr = l >> 4;
    const int fr  = l & 15;

    f4v acc[2][2];
#pragma unroll
    for (int m = 0; m < 2; ++m)
#pragma unroll
        for (int n2 = 0; n2 < 2; ++n2) acc[m][n2] = f4v{0.f, 0.f, 0.f, 0.f};

    const int nk = K / 32;
    float4 a0 = *(const float4*)(aRow + kg * 8);
    float4 a1 = *(const float4*)(aRow + kg * 8 + 4);
    float4 w0 = *(const float4*)(wRow + kg * 8);
    float4 w1 = *(const float4*)(wRow + kg * 8 + 4);

    for (int kc = 0; kc < nk; ++kc) {
        bh8 av = { f2bf(a0.x), f2bf(a0.y), f2bf(a0.z), f2bf(a0.w),
                   f2bf(a1.x), f2bf(a1.y), f2bf(a1.z), f2bf(a1.w) };
        bh8 wv8= { f2bf(w0.x), f2bf(w0.y), f2bf(w0.z), f2bf(w0.w),
                   f2bf(w1.x), f2bf(w1.y), f2bf(w1.z), f2bf(w1.w) };
        __syncthreads();
        *(bh8*)(sA + swzSt) = av;
        *(bh8*)(sW + swzSt) = wv8;
        __syncthreads();
        if (kc + 1 < nk) {
            const int k0 = (kc + 1) * 32 + kg * 8;
            a0 = *(const float4*)(aRow + k0);
            a1 = *(const float4*)(aRow + k0 + 4);
            w0 = *(const float4*)(wRow + k0);
            w1 = *(const float4*)(wRow + k0 + 4);
        }
        bh8 af[2], bf[2];
#pragma unroll
        for (int m = 0; m < 2; ++m) {
            int ar = wr * 32 + m * 16 + fr;
            af[m] = *(bh8*)(sA + ar * 32 + ((kgr ^ (ar & 3)) << 3));
            int bc = wc * 32 + m * 16 + fr;
            bf[m] = *(bh8*)(sW + bc * 32 + ((kgr ^ (bc & 3)) << 3));
        }
#pragma unroll
        for (int m = 0; m < 2; ++m)
#pragma unroll
            for (int n2 = 0; n2 < 2; ++n2)
                acc[m][n2] = __builtin_amdgcn_mfma_f32_16x16x32_bf16(
                    af[m], bf[n2], acc[m][n2], 0, 0, 0);
    }

#pragma unroll
    for (int n2 = 0; n2 < 2; ++n2) {
        const int colg = bj + wc * 32 + n2 * 16 + fr;
        const float bs = bias[colg];
#pragma unroll
        for (int m = 0; m < 2; ++m)
#pragma unroll
            for (int rg = 0; rg < 4; ++rg) {
                const int rowg = bm + wr * 32 + m * 16 + kgr * 4 + rg;
                out[(size_t)rowg * J + colg] = acc[m][n2][rg] + bs;
            }
    }
}

// ---------------------------------------------------------------------------
// GEMM_C: ev[n,j] = act( h_o[n,:256] . Wrow(j) + b(j) ), j<128 -> sigmoid(We),
// j>=128 -> Wv. J=256, K=256. Same structure + prefetch.
// ---------------------------------------------------------------------------
__global__ __launch_bounds__(256) void gemm_ev(
    const float* __restrict__ A,
    const float* __restrict__ We, const float* __restrict__ Wv,
    const float* __restrict__ be, const float* __restrict__ bv,
    float* __restrict__ out)
{
    constexpr int K = 256, J = 256;
    __shared__ __align__(16) short sA[64 * 32];
    __shared__ __align__(16) short sW[64 * 32];

    const int t  = threadIdx.x;
    const int bm = blockIdx.x * 64;
    const int bj = blockIdx.y * 64;

    const int r  = t >> 2;
    const int kg = t & 3;
    const float* aRow = A + (size_t)(bm + r) * K;
    const int colS = bj + r;
    const float* wRow = (colS < 128) ? (We + (size_t)colS * K)
                                     : (Wv + (size_t)(colS - 128) * K);
    const int swzSt = r * 32 + ((kg ^ (r & 3)) << 3);

    const int l   = t & 63;
    const int wv  = t >> 6;
    const int wr  = wv >> 1;
    const int wc  = wv & 1;
    const int kgr = l >> 4;
    const int fr  = l & 15;

    f4v acc[2][2];
#pragma unroll
    for (int m = 0; m < 2; ++m)
#pragma unroll
        for (int n2 = 0; n2 < 2; ++n2) acc[m][n2] = f4v{0.f, 0.f, 0.f, 0.f};

    const int nk = K / 32;
    float4 a0 = *(const float4*)(aRow + kg * 8);
    float4 a1 = *(const float4*)(aRow + kg * 8 + 4);
    float4 w0 = *(const float4*)(wRow + kg * 8);
    float4 w1 = *(const float4*)(wRow + kg * 8 + 4);

    for (int kc = 0; kc < nk; ++kc) {
        bh8 av = { f2bf(a0.x), f2bf(a0.y), f2bf(a0.z), f2bf(a0.w),
                   f2bf(a1.x), f2bf(a1.y), f2bf(a1.z), f2bf(a1.w) };
        bh8 wv8= { f2bf(w0.x), f2bf(w0.y), f2bf(w0.z), f2bf(w0.w),
                   f2bf(w1.x), f2bf(w1.y), f2bf(w1.z), f2bf(w1.w) };
        __syncthreads();
        *(bh8*)(sA + swzSt) = av;
        *(bh8*)(sW + swzSt) = wv8;
        __syncthreads();
        if (kc + 1 < nk) {
            const int k0 = (kc + 1) * 32 + kg * 8;
            a0 = *(const float4*)(aRow + k0);
            a1 = *(const float4*)(aRow + k0 + 4);
            w0 = *(const float4*)(wRow + k0);
            w1 = *(const float4*)(wRow + k0 + 4);
        }
        bh8 af[2], bf[2];
#pragma unroll
        for (int m = 0; m < 2; ++m) {
            int ar = wr * 32 + m * 16 + fr;
            af[m] = *(bh8*)(sA + ar * 32 + ((kgr ^ (ar & 3)) << 3));
            int bc = wc * 32 + m * 16 + fr;
            bf[m] = *(bh8*)(sW + bc * 32 + ((kgr ^ (bc & 3)) << 3));
        }
#pragma unroll
        for (int m = 0; m < 2; ++m)
#pragma unroll
            for (int n2 = 0; n2 < 2; ++n2)
                acc[m][n2] = __builtin_amdgcn_mfma_f32_16x16x32_bf16(
                    af[m], bf[n2], acc[m][n2], 0, 0, 0);
    }

#pragma unroll
    for (int n2 = 0; n2 < 2; ++n2) {
        const int colg = bj + wc * 32 + n2 * 16 + fr;
        const float bs = (colg < 128) ? be[colg] : bv[colg - 128];
#pragma unroll
        for (int m = 0; m < 2; ++m)
#pragma unroll
            for (int rg = 0; rg < 4; ++rg) {
                float x = acc[m][n2][rg] + bs;
                if (colg < 128) x = sigmf(x);
                const int rowg = bm + wr * 32 + m * 16 + kgr * 4 + rg;
                out[(size_t)rowg * J + colg] = x;
            }
    }
}

// ---------------------------------------------------------------------------
// Attention mega-kernel, one block per n:
//   k = Wk @ h + bk (fp32 GEMV, Wk from L2), beta = softplus(Wb.h+bb)+1,
//   scores (C read once from HBM, staged to LDS as bf16), softmax -> w,
//   r = w^T C from LDS.
// ---------------------------------------------------------------------------
__global__ __launch_bounds__(256) void attn_kernel(
    const float* __restrict__ C, const float* __restrict__ h_prev,
    const float* __restrict__ Wk, const float* __restrict__ bk,
    const float* __restrict__ Wb, const float* __restrict__ bb,
    float* __restrict__ k_out, float* __restrict__ w_out, float* __restrict__ r_out)
{
    const int n    = blockIdx.x;
    const int t    = threadIdx.x;
    const int lane = t & 63;
    const int wid  = t >> 6;
    const float* Cn = C + (size_t)n * Ss * Ff;

    __shared__ float sH[Dd];
    __shared__ float sk[Ff];
    __shared__ __align__(16) short sC[Ss * Ff];   // bf16 tile, 32 KiB
    __shared__ float ssc[Ss];
    __shared__ float sw[Ss];
    __shared__ float sred[16];
    __shared__ float sr4[8][Ff];

    sH[t] = h_prev[(size_t)n * Dd + t];
    __syncthreads();

    // ---- k GEMV: j = t>>1, half = t&1 covers d-range [half*128, +128)
    {
        const int j = t >> 1, half = t & 1;
        const float* wr = Wk + (size_t)j * Dd + half * 128;
        const float* hh = sH + half * 128;
        float acc = 0.0f;
#pragma unroll 8
        for (int d4 = 0; d4 < 128; d4 += 4) {
            float4 wv = *(const float4*)(wr + d4);
            float4 hv = *(const float4*)(hh + d4);
            acc += wv.x * hv.x + wv.y * hv.y + wv.z * hv.z + wv.w * hv.w;
        }
        acc += __shfl_xor(acc, 1);
        if (half == 0) {
            float kv = acc + bk[j];
            sk[j] = kv;
            k_out[(size_t)n * Ff + j] = kv;
        }
    }
    // ---- beta partial (wave 0): dot(h, Wb)
    if (t < 64) {
        float4 hv = *(const float4*)(sH + t * 4);
        float4 wv = *(const float4*)(Wb + t * 4);
        float p = hv.x * wv.x + hv.y * wv.y + hv.z * wv.z + hv.w * wv.w;
#pragma unroll
        for (int o = 32; o > 0; o >>= 1) p += __shfl_xor(p, o);
        if (t == 0) sred[8] = p;
    }
    __syncthreads();

    // ---- knorm
    if (t < Ss) {
        float kv = sk[t];
        float ks = kv * kv;
#pragma unroll
        for (int o = 32; o > 0; o >>= 1) ks += __shfl_xor(ks, o);
        if (lane == 0) sred[wid] = ks;
    }
    __syncthreads();
    const float knorm = fmaxf(sqrtf(sred[0] + sred[1]), EPSV);
    float bp = sred[8] + bb[0];
    const float beta = ((bp > 20.0f) ? bp : log1pf(__expf(bp))) + 1.0f;

    // ---- pass 1: scores + stage C to LDS (bf16)
#pragma unroll 4
    for (int it = 0; it < 16; ++it) {
        int s = wid * 32 + it * 2 + (lane >> 5);
        int f = (lane & 31) * 4;
        float4 c4 = *(const float4*)(Cn + (size_t)s * Ff + f);
        bh4 cb = { f2bf(c4.x), f2bf(c4.y), f2bf(c4.z), f2bf(c4.w) };
        *(bh4*)(sC + s * Ff + f) = cb;
        float d = c4.x * sk[f] + c4.y * sk[f + 1] + c4.z * sk[f + 2] + c4.w * sk[f + 3];
        float q = c4.x * c4.x + c4.y * c4.y + c4.z * c4.z + c4.w * c4.w;
#pragma unroll
        for (int o = 16; o > 0; o >>= 1) {
            d += __shfl_xor(d, o);
            q += __shfl_xor(q, o);
        }
        if ((lane & 31) == 0) {
            float cn = fmaxf(sqrtf(q), EPSV);
            ssc[s] = d / (cn * knorm);
        }
    }
    __syncthreads();

    // ---- softmax (threads 0..127)
    float x = -INFINITY;
    if (t < Ss) x = ssc[t] * beta;
    float m = x;
#pragma unroll
    for (int o = 32; o > 0; o >>= 1) m = fmaxf(m, __shfl_xor(m, o));
    if (lane == 0) sred[wid] = m;
    __syncthreads();
    const float gm = fmaxf(sred[0], sred[1]);
    float ex = (t < Ss) ? __expf(x - gm) : 0.0f;
    float sm = ex;
#pragma unroll
    for (int o = 32; o > 0; o >>= 1) sm += __shfl_xor(sm, o);
    if (lane == 0) sred[4 + wid] = sm;
    __syncthreads();
    const float tot = sred[4] + sred[5];
    if (t < Ss) {
        float wvl = ex / tot;
        sw[t] = wvl;
        w_out[(size_t)n * Ss + t] = wvl;
    }
    __syncthreads();

    // ---- pass 2: r from LDS bf16 tile
    const int f4 = (t & 31) * 4;
    const int sg = t >> 5;
    float4 racc = make_float4(0.f, 0.f, 0.f, 0.f);
#pragma unroll 4
    for (int j = 0; j < 16; ++j) {
        int s = sg * 16 + j;
        float wvl = sw[s];
        bh4 cb = *(const bh4*)(sC + s * Ff + f4);
        racc.x += wvl * bf2f(cb.x);
        racc.y += wvl * bf2f(cb.y);
        racc.z += wvl * bf2f(cb.z);
        racc.w += wvl * bf2f(cb.w);
    }
    *(float4*)(&sr4[sg][f4]) = racc;
    __syncthreads();
    if (t < 32) {
        float4 rr = *(float4*)(&sr4[0][t * 4]);
#pragma unroll
        for (int g = 1; g < 8; ++g) {
            float4 p = *(float4*)(&sr4[g][t * 4]);
            rr.x += p.x; rr.y += p.y; rr.z += p.z; rr.w += p.w;
        }
        *(float4*)(r_out + (size_t)n * Ff + t * 4) = rr;
    }
}

// ---------------------------------------------------------------------------
// Gates: h_o = (1-z)*tanh(i_n + rg*h_n) + z*h_prev
// ---------------------------------------------------------------------------
__global__ __launch_bounds__(256) void gates_kernel(
    const float* __restrict__ gi, const float* __restrict__ gh,
    const float* __restrict__ hprev, float* __restrict__ ho)
{
    int idx = blockIdx.x * blockDim.x + threadIdx.x;
    int n  = idx >> 6;
    int d4 = (idx & 63) * 4;
    const float* gin = gi + (size_t)n * 768;
    const float* ghn = gh + (size_t)n * 768;
    float4 ir = *(const float4*)(gin + d4);
    float4 iz = *(const float4*)(gin + 256 + d4);
    float4 in_ = *(const float4*)(gin + 512 + d4);
    float4 hr = *(const float4*)(ghn + d4);
    float4 hz = *(const float4*)(ghn + 256 + d4);
    float4 hn = *(const float4*)(ghn + 512 + d4);
    float4 hp = *(const float4*)(hprev + (size_t)n * Dd + d4);
    float4 o;
    { float rg = sigmf(ir.x + hr.x); float z = sigmf(iz.x + hz.x);
      float nn = tanhf(in_.x + rg * hn.x); o.x = (1.0f - z) * nn + z * hp.x; }
    { float rg = sigmf(ir.y + hr.y); float z = sigmf(iz.y + hz.y);
      float nn = tanhf(in_.y + rg * hn.y); o.y = (1.0f - z) * nn + z * hp.y; }
    { float rg = sigmf(ir.z + hr.z); float z = sigmf(iz.z + hz.z);
      float nn = tanhf(in_.z + rg * hn.z); o.z = (1.0f - z) * nn + z * hp.z; }
    { float rg = sigmf(ir.w + hr.w); float z = sigmf(iz.w + hz.w);
      float nn = tanhf(in_.w + rg * hn.w); o.w = (1.0f - z) * nn + z * hp.w; }
    *(float4*)(ho + (size_t)n * Dd + d4) = o;
}

// ---------------------------------------------------------------------------
// C_new = C*(1 - w*e) + w*v. Descending order + NT so the L3-resident tail of
// C (left by attn's regular reads) is hit and not evicted by the write stream.
// ---------------------------------------------------------------------------
__global__ __launch_bounds__(256) void update_kernel(
    const float* __restrict__ C, const float* __restrict__ w,
    const float* __restrict__ ev, float* __restrict__ Cnew)
{
    const size_t total4 = (size_t)Nn * Ss * Ff / 4;
    const size_t stride = (size_t)gridDim.x * blockDim.x;
    const size_t lin    = (size_t)blockIdx.x * blockDim.x + threadIdx.x;
    const int nIter     = (int)(total4 / stride);
    for (int it = nIter - 1; it >= 0; --it) {
        size_t i = (size_t)it * stride + lin;
        int n   = (int)(i >> 12);
        int rem = (int)(i & 4095);
        int s   = rem >> 5;
        int f4  = (rem & 31) * 4;
        float wv = w[(size_t)n * Ss + s];
        float4 e4 = *(const float4*)(ev + (size_t)n * 256 + f4);
        float4 v4 = *(const float4*)(ev + (size_t)n * 256 + 128 + f4);
        f4v c4 = __builtin_nontemporal_load((const f4v*)(C + i * 4));
        f4v o;
        o.x = c4.x * (1.0f - wv * e4.x) + wv * v4.x;
        o.y = c4.y * (1.0f - wv * e4.y) + wv * v4.y;
        o.z = c4.z * (1.0f - wv * e4.z) + wv * v4.z;
        o.w = c4.w * (1.0f - wv * e4.w) + wv * v4.w;
        __builtin_nontemporal_store(o, (f4v*)(Cnew + i * 4));
    }
}

// ---------------------------------------------------------------------------
extern "C" void kernel_launch(void* const* d_in, const int* in_sizes, int n_in,
                              void* d_out, int out_size, void* d_ws, size_t ws_size,
                              hipStream_t stream)
{
    const float* h_prev = (const float*)d_in[0];
    const float* C      = (const float*)d_in[1];
    const float* Wk     = (const float*)d_in[2];
    const float* bk     = (const float*)d_in[3];
    const float* Wb     = (const float*)d_in[4];
    const float* bb     = (const float*)d_in[5];
    const float* We     = (const float*)d_in[6];
    const float* be     = (const float*)d_in[7];
    const float* Wv     = (const float*)d_in[8];
    const float* bv     = (const float*)d_in[9];
    const float* Wih    = (const float*)d_in[10];
    const float* Whh    = (const float*)d_in[11];
    const float* bih    = (const float*)d_in[12];
    const float* bhh    = (const float*)d_in[13];

    float* out  = (float*)d_out;
    float* ho   = out + HO_OFF;
    float* Cnew = out + C_OFF;
    float* kbuf = out + K_OFF;
    float* rbuf = out + R_OFF;

    float* ws    = (float*)d_ws;
    float* ws_gh = ws;                          // N*768
    float* ws_gi = ws_gh + (size_t)Nn * 768;    // N*768
    float* ws_w  = ws_gi + (size_t)Nn * 768;    // N*128
    float* ws_ev = ws_w + (size_t)Nn * Ss;      // N*256

    // 1) attention (computes k, beta in-block; C staged to LDS)
    attn_kernel<<<Nn, 256, 0, stream>>>(C, h_prev, Wk, bk, Wb, bb,
                                        kbuf, ws_w, rbuf);

    // 2) dual GEMM: z=0 gh = h_prev@Whh.T (K=256); z=1 gi = r@Wih.T (K=128)
    gemm_dual<<<dim3(Nn / 64, 768 / 64, 2), 256, 0, stream>>>(
        h_prev, Dd, Whh, bhh, ws_gh,
        rbuf,   Ff, Wih, bih, ws_gi, 768);

    // 3) gates -> h_o
    gates_kernel<<<(Nn * Dd / 4) / 256, 256, 0, stream>>>(ws_gi, ws_gh, h_prev, ho);

    // 4) [e|v] = h_o @ [We;Wv].T, sigmoid on e
    gemm_ev<<<dim3(Nn / 64, 256 / 64), 256, 0, stream>>>(ho, We, Wv, be, bv, ws_ev);

    // 5) update -> C_new
    update_kernel<<<8192, 256, 0, stream>>>(C, ws_w, ws_ev, Cnew);
}

// Round 5
// 190.963 us; speedup vs baseline: 1.2458x; 1.2458x over previous
//
#include <hip/hip_runtime.h>
#include <hip/hip_bf16.h>
#include <cstddef>
#include <cstdint>

// Problem dims
constexpr int Nn = 4096;
constexpr int Ss = 128;
constexpr int Ff = 128;
constexpr int Dd = 256;
constexpr float EPSV = 1e-8f;

// d_out layout (floats): h_o [N*D], C_new [N*S*F], k [N*F], r [N*F]
constexpr size_t HO_OFF = 0;
constexpr size_t C_OFF  = (size_t)Nn * Dd;
constexpr size_t K_OFF  = C_OFF + (size_t)Nn * Ss * Ff;
constexpr size_t R_OFF  = K_OFF + (size_t)Nn * Ff;

typedef __attribute__((ext_vector_type(4))) float f4v;
typedef __attribute__((ext_vector_type(8))) short bh8;
typedef __attribute__((ext_vector_type(4))) short bh4;

// bf16 weight pack offsets in ws (units: shorts)
constexpr int WK_O  = 0;        // Wk   128x256
constexpr int WHH_O = 32768;    // Whh  768x256
constexpr int WIH_O = 229376;   // Wih  768x128
constexpr int WEV_O = 327680;   // [We;Wv] 256x256
constexpr int W_TOT = 393216;

__device__ __forceinline__ float sigmf(float x) { return 1.0f / (1.0f + __expf(-x)); }

__device__ __forceinline__ short f2bf(float x) {
    __hip_bfloat16 h = __float2bfloat16(x);   // RNE
    return *reinterpret_cast<short*>(&h);
}

// XOR swizzle: spread 16B k-slots of row r across banks. Row strides 512B / 256B.
__device__ __forceinline__ int swzH(int row, int kb) { return row * 512 + (kb ^ ((row & 7) << 4)); }
__device__ __forceinline__ int swzR(int row, int kb) { return row * 256 + (kb ^ ((row & 7) << 4)); }

__device__ __forceinline__ f4v mfma16(bh8 a, bh8 b, f4v c) {
    return __builtin_amdgcn_mfma_f32_16x16x32_bf16(a, b, c, 0, 0, 0);
}

// ---------------------------------------------------------------------------
// Prep: convert all weights to bf16, packed row-major into ws.
// ---------------------------------------------------------------------------
__global__ __launch_bounds__(256) void prep_weights(
    const float* __restrict__ Wk, const float* __restrict__ Whh,
    const float* __restrict__ Wih, const float* __restrict__ We,
    const float* __restrict__ Wv, short* __restrict__ out)
{
    int id = blockIdx.x * 256 + threadIdx.x;   // grid covers W_TOT exactly
    float v;
    if      (id < WHH_O) v = Wk[id - WK_O];
    else if (id < WIH_O) v = Whh[id - WHH_O];
    else if (id < WEV_O) v = Wih[id - WIH_O];
    else if (id < WEV_O + 32768) v = We[id - WEV_O];
    else v = Wv[id - WEV_O - 32768];
    out[id] = f2bf(v);
}

// ---------------------------------------------------------------------------
// Mega kernel: 512 blocks x 512 threads; block handles 8 rows, wave w = row w
// for per-row phases. Phases:
//  P0 load h (fp32 + swizzled bf16, zero pads)
//  P1 k = h@Wk^T + bk                       [MFMA, all waves]
//  P2 per-row: knorm, beta, ONE pass over C: scores + online-softmax r
//  P3 gh+gi fused gates pre-activations     [MFMA, all waves]
//  P4 per-row gates -> h_o (global + swizzled bf16 LDS)
//  P5 [e|v] = sig/lin(h_o@[We;Wv]^T)        [MFMA, all waves]
//  P6 per-row: C_new = C*(1-w*e)+w*v  (C re-read is L2/L3-hot, NT store)
// ---------------------------------------------------------------------------
__global__ __launch_bounds__(512, 4) void mega_kernel(
    const float* __restrict__ C, const float* __restrict__ h_prev,
    const short* __restrict__ WB,
    const float* __restrict__ Wb, const float* __restrict__ bb,
    const float* __restrict__ bk, const float* __restrict__ bhh,
    const float* __restrict__ bih, const float* __restrict__ be,
    const float* __restrict__ bv,
    float* __restrict__ ho, float* __restrict__ Cnew,
    float* __restrict__ kout, float* __restrict__ rout)
{
    __shared__ float sH[8][256];                  // h_prev fp32
    __shared__ __align__(16) short sHb[16 * 256]; // h (later h_o) bf16, 16-row pad, swizzled
    __shared__ __align__(16) short sRb[16 * 128]; // r bf16, 16-row pad, swizzled
    __shared__ float sK[8][128];
    __shared__ float sSc[8][128];                 // scores (pre-softmax, *beta)
    __shared__ float sGs[8][768];                 // [0,512): gi+gh summed; [512,768): h_n only
    __shared__ float sGn[8][256];                 // i_n
    __shared__ float sEV[8][256];                 // e | v

    const int t  = threadIdx.x;
    const int l  = t & 63;
    const int wv = t >> 6;
    const int nb = blockIdx.x * 8;
    char* hb = (char*)sHb;
    char* rb = (char*)sRb;

    const short* WkB  = WB + WK_O;
    const short* WhhB = WB + WHH_O;
    const short* WihB = WB + WIH_O;
    const short* WevB = WB + WEV_O;

    // ---- P0: load h rows, build bf16 copies, zero pad rows
    {
        const int f = t * 4, row = f >> 8, col = f & 255;
        float4 hv = *(const float4*)(h_prev + (size_t)(nb + row) * Dd + col);
        *(float4*)&sH[row][col] = hv;
        bh4 hb4 = { f2bf(hv.x), f2bf(hv.y), f2bf(hv.z), f2bf(hv.w) };
        *(bh4*)(hb + swzH(row, col * 2)) = hb4;
        *(int4*)(hb + 8192 + t * 16) = int4{0, 0, 0, 0};   // sHb rows 8..15 = 0
        *(int*)(rb + 2048 + t * 4) = 0;                    // sRb rows 8..15 = 0
    }
    __syncthreads();

    // ---- P1: k = h @ Wk^T + bk (each wave: one 16-col tile, all rows)
    {
        const int fr = l & 15, kq = l >> 4, rbase = kq * 4;
        const int colg = wv * 16 + fr;
        f4v acc = {0.f, 0.f, 0.f, 0.f};
#pragma unroll
        for (int kc = 0; kc < 8; ++kc) {
            bh8 a = *(const bh8*)(hb + swzH(fr, kc * 64 + kq * 16));
            bh8 b = *(const bh8*)(WkB + (size_t)colg * 256 + kc * 32 + kq * 8);
            acc = mfma16(a, b, acc);
        }
        if (rbase < 8) {
            const float bs = bk[colg];
#pragma unroll
            for (int rg = 0; rg < 4; ++rg) {
                float x = acc[rg] + bs;
                sK[rbase + rg][colg] = x;
                kout[(size_t)(nb + rbase + rg) * Ff + colg] = x;
            }
        }
    }
    __syncthreads();

    // ---- P2: per-row attention, single pass over C with online softmax-r
    float M_r = 0.0f, invL_r = 0.0f;   // live to P6
    {
        const int half = l >> 5, fl = l & 31, f4 = fl * 4;
        const float* Cn = C + (size_t)(nb + wv) * (Ss * Ff);

        float kv0 = sK[wv][l], kv1 = sK[wv][64 + l];
        float ks = kv0 * kv0 + kv1 * kv1;
#pragma unroll
        for (int o = 32; o > 0; o >>= 1) ks += __shfl_xor(ks, o);
        const float knorm = fmaxf(sqrtf(ks), EPSV);

        float4 hv = *(const float4*)&sH[wv][l * 4];
        float4 wb4 = *(const float4*)(Wb + l * 4);
        float bp = hv.x * wb4.x + hv.y * wb4.y + hv.z * wb4.z + hv.w * wb4.w;
#pragma unroll
        for (int o = 32; o > 0; o >>= 1) bp += __shfl_xor(bp, o);
        bp += bb[0];
        const float beta = ((bp > 20.0f) ? bp : log1pf(__expf(bp))) + 1.0f;

        const float4 kreg = *(const float4*)&sK[wv][f4];
        float m = -INFINITY, lsum = 0.0f;
        f4v racc = {0.f, 0.f, 0.f, 0.f};
#pragma unroll 4
        for (int it = 0; it < 64; ++it) {
            const int s = it * 2 + half;
            f4v c4 = *(const f4v*)(Cn + s * Ff + f4);
            float d = c4.x * kreg.x + c4.y * kreg.y + c4.z * kreg.z + c4.w * kreg.w;
            float q = c4.x * c4.x + c4.y * c4.y + c4.z * c4.z + c4.w * c4.w;
#pragma unroll
            for (int o = 16; o > 0; o >>= 1) { d += __shfl_xor(d, o); q += __shfl_xor(q, o); }
            const float x = d / (fmaxf(sqrtf(q), EPSV) * knorm) * beta;
            if (fl == 0) sSc[wv][s] = x;
            const float mn   = fmaxf(m, x);
            const float corr = __expf(m - mn);   // first iter: exp(-inf)=0
            const float p    = __expf(x - mn);
            lsum = lsum * corr + p;
            racc = racc * corr + p * c4;
            m = mn;
        }
        // combine even/odd-s halves
        float m2 = __shfl_xor(m, 32);
        float l2 = __shfl_xor(lsum, 32);
        f4v r2;
        r2.x = __shfl_xor(racc.x, 32); r2.y = __shfl_xor(racc.y, 32);
        r2.z = __shfl_xor(racc.z, 32); r2.w = __shfl_xor(racc.w, 32);
        const float M  = fmaxf(m, m2);
        const float e1 = __expf(m - M), e2 = __expf(m2 - M);
        const float L  = lsum * e1 + l2 * e2;
        const float iL = 1.0f / L;
        f4v r4 = (racc * e1 + r2 * e2) * iL;
        if (half == 0) {
            *(f4v*)(rout + (size_t)(nb + wv) * Ff + f4) = r4;
            bh4 rb4 = { f2bf(r4.x), f2bf(r4.y), f2bf(r4.z), f2bf(r4.w) };
            *(bh4*)(rb + swzR(wv, f4 * 2)) = rb4;
        }
        M_r = M; invL_r = iL;
    }
    __syncthreads();

    // ---- P3: gh = h@Whh^T + bhh; gi = r@Wih^T + bih; store sums / n-parts
    {
        const int fr = l & 15, kq = l >> 4, rbase = kq * 4;
#pragma unroll
        for (int i = 0; i < 6; ++i) {
            const int colg = i * 128 + wv * 16 + fr;
            f4v aG = {0.f, 0.f, 0.f, 0.f}, aI = {0.f, 0.f, 0.f, 0.f};
#pragma unroll
            for (int kc = 0; kc < 8; ++kc) {
                bh8 a = *(const bh8*)(hb + swzH(fr, kc * 64 + kq * 16));
                bh8 b = *(const bh8*)(WhhB + (size_t)colg * 256 + kc * 32 + kq * 8);
                aG = mfma16(a, b, aG);
            }
#pragma unroll
            for (int kc = 0; kc < 4; ++kc) {
                bh8 a = *(const bh8*)(rb + swzR(fr, kc * 64 + kq * 16));
                bh8 b = *(const bh8*)(WihB + (size_t)colg * 128 + kc * 32 + kq * 8);
                aI = mfma16(a, b, aI);
            }
            if (rbase < 8) {
                if (colg < 512) {
                    const float bs = bhh[colg] + bih[colg];
#pragma unroll
                    for (int rg = 0; rg < 4; ++rg)
                        sGs[rbase + rg][colg] = aG[rg] + aI[rg] + bs;
                } else {   // n-gate: keep h_n and i_n separate
                    const float b1 = bhh[colg], b2 = bih[colg];
#pragma unroll
                    for (int rg = 0; rg < 4; ++rg) {
                        sGs[rbase + rg][colg]       = aG[rg] + b1;
                        sGn[rbase + rg][colg - 512] = aI[rg] + b2;
                    }
                }
            }
        }
    }
    __syncthreads();

    // ---- P4: gates -> h_o (wave w, row w; lane covers 4 d's)
    {
        const int d4 = l * 4;
        float4 gr  = *(const float4*)&sGs[wv][d4];
        float4 gz  = *(const float4*)&sGs[wv][256 + d4];
        float4 hn  = *(const float4*)&sGs[wv][512 + d4];
        float4 in_ = *(const float4*)&sGn[wv][d4];
        float4 hp  = *(const float4*)&sH[wv][d4];
        float4 o;
        { float rg = sigmf(gr.x), z = sigmf(gz.x);
          float nn = tanhf(in_.x + rg * hn.x); o.x = (1.0f - z) * nn + z * hp.x; }
        { float rg = sigmf(gr.y), z = sigmf(gz.y);
          float nn = tanhf(in_.y + rg * hn.y); o.y = (1.0f - z) * nn + z * hp.y; }
        { float rg = sigmf(gr.z), z = sigmf(gz.z);
          float nn = tanhf(in_.z + rg * hn.z); o.z = (1.0f - z) * nn + z * hp.z; }
        { float rg = sigmf(gr.w), z = sigmf(gz.w);
          float nn = tanhf(in_.w + rg * hn.w); o.w = (1.0f - z) * nn + z * hp.w; }
        *(float4*)(ho + (size_t)(nb + wv) * Dd + d4) = o;
        bh4 ob = { f2bf(o.x), f2bf(o.y), f2bf(o.z), f2bf(o.w) };
        *(bh4*)(hb + swzH(wv, d4 * 2)) = ob;    // sHb now holds h_o
    }
    __syncthreads();

    // ---- P5: [e|v] = h_o @ [We;Wv]^T (+sigmoid on e)
    {
        const int fr = l & 15, kq = l >> 4, rbase = kq * 4;
#pragma unroll
        for (int i = 0; i < 2; ++i) {
            const int colg = i * 128 + wv * 16 + fr;
            f4v acc = {0.f, 0.f, 0.f, 0.f};
#pragma unroll
            for (int kc = 0; kc < 8; ++kc) {
                bh8 a = *(const bh8*)(hb + swzH(fr, kc * 64 + kq * 16));
                bh8 b = *(const bh8*)(WevB + (size_t)colg * 256 + kc * 32 + kq * 8);
                acc = mfma16(a, b, acc);
            }
            if (rbase < 8) {
                const float bs = (colg < 128) ? be[colg] : bv[colg - 128];
#pragma unroll
                for (int rg = 0; rg < 4; ++rg) {
                    float x = acc[rg] + bs;
                    if (colg < 128) x = sigmf(x);
                    sEV[rbase + rg][colg] = x;
                }
            }
        }
    }
    __syncthreads();

    // ---- P6: C_new = C*(1 - w*e) + w*v  (C re-read L2/L3-hot; NT store)
    {
        const int half = l >> 5, fl = l & 31, f4 = fl * 4;
        const float* Cn = C    + (size_t)(nb + wv) * (Ss * Ff);
        float*       Co = Cnew + (size_t)(nb + wv) * (Ss * Ff);
        f4v e4 = *(const f4v*)&sEV[wv][f4];
        f4v v4 = *(const f4v*)&sEV[wv][128 + f4];
#pragma unroll 4
        for (int it = 0; it < 64; ++it) {
            const int s = it * 2 + half;
            const float wsc = __expf(sSc[wv][s] - M_r) * invL_r;
            f4v c4 = *(const f4v*)(Cn + s * Ff + f4);
            f4v o = c4 * (1.0f - wsc * e4) + wsc * v4;
            __builtin_nontemporal_store(o, (f4v*)(Co + s * Ff + f4));
        }
    }
}

// ---------------------------------------------------------------------------
extern "C" void kernel_launch(void* const* d_in, const int* in_sizes, int n_in,
                              void* d_out, int out_size, void* d_ws, size_t ws_size,
                              hipStream_t stream)
{
    const float* h_prev = (const float*)d_in[0];
    const float* C      = (const float*)d_in[1];
    const float* Wk     = (const float*)d_in[2];
    const float* bk     = (const float*)d_in[3];
    const float* Wb     = (const float*)d_in[4];
    const float* bb     = (const float*)d_in[5];
    const float* We     = (const float*)d_in[6];
    const float* be     = (const float*)d_in[7];
    const float* Wv     = (const float*)d_in[8];
    const float* bv     = (const float*)d_in[9];
    const float* Wih    = (const float*)d_in[10];
    const float* Whh    = (const float*)d_in[11];
    const float* bih    = (const float*)d_in[12];
    const float* bhh    = (const float*)d_in[13];

    float* out  = (float*)d_out;
    float* ho   = out + HO_OFF;
    float* Cnew = out + C_OFF;
    float* kbuf = out + K_OFF;
    float* rbuf = out + R_OFF;

    short* wsB = (short*)d_ws;

    prep_weights<<<W_TOT / 256, 256, 0, stream>>>(Wk, Whh, Wih, We, Wv, wsB);

    mega_kernel<<<Nn / 8, 512, 0, stream>>>(
        C, h_prev, wsB, Wb, bb, bk, bhh, bih, be, bv,
        ho, Cnew, kbuf, rbuf);
}